// Round 1
// baseline (703.621 us; speedup 1.0000x reference)
//
#include <hip/hip_runtime.h>
#include <hip/hip_bf16.h>

// ---------------- static problem constants ----------------
static constexpr int BS     = 4;
static constexpr int EMBED  = 256;
static constexpr int HEADS  = 8;
static constexpr int LEVELS = 4;
static constexpr int POINTS = 4;
static constexpr int HD     = 32;               // EMBED / HEADS
static constexpr int LQ     = 12240;            // sum of level areas
static constexpr int NROW   = BS * LQ;          // 48960 rows
static constexpr int LVL_W[4]  = {96, 48, 24, 12};
static constexpr int LVL_H[4]  = {96, 48, 24, 12};
static constexpr int LVL_ST[4] = {0, 9216, 11520, 12096};

// ---------------- f32 tiled GEMM:  C[M,N] = A[M,K] @ W[K,N] + bias[N] ----------------
// BM=BN=64, BK=16, 256 threads, 4x4 micro-tile per thread. M%64==0, N%64==0, K%16==0.
#define BM 64
#define BN 64
#define BK 16

__global__ __launch_bounds__(256) void gemm_bias(
    const float* __restrict__ A, const float* __restrict__ W,
    const float* __restrict__ bias, float* __restrict__ C,
    int M, int N, int K)
{
    __shared__ float As[BK][BM + 1];   // [k][m], +1 pad to break store conflicts
    __shared__ float Bs[BK][BN];       // [k][n]

    const int tid = threadIdx.x;
    const int tx = tid & 15;           // 0..15 -> n
    const int ty = tid >> 4;           // 0..15 -> m
    const int row0 = blockIdx.y * BM;
    const int col0 = blockIdx.x * BN;

    float acc[4][4] = {};

    for (int k0 = 0; k0 < K; k0 += BK) {
        // A tile: 64 rows x 16 k. Each thread: one float4 along K.
        {
            const int r  = tid >> 2;             // 0..63
            const int kk = (tid & 3) * 4;        // 0,4,8,12
            const float4 a4 = *(const float4*)&A[(size_t)(row0 + r) * K + k0 + kk];
            As[kk + 0][r] = a4.x;
            As[kk + 1][r] = a4.y;
            As[kk + 2][r] = a4.z;
            As[kk + 3][r] = a4.w;
        }
        // B tile: 16 k x 64 n. Each thread: one float4 along N.
        {
            const int kk = tid >> 4;             // 0..15
            const int c  = (tid & 15) * 4;       // 0..60
            const float4 b4 = *(const float4*)&W[(size_t)(k0 + kk) * N + col0 + c];
            Bs[kk][c + 0] = b4.x;
            Bs[kk][c + 1] = b4.y;
            Bs[kk][c + 2] = b4.z;
            Bs[kk][c + 3] = b4.w;
        }
        __syncthreads();

        #pragma unroll
        for (int k = 0; k < BK; ++k) {
            float a[4], b[4];
            #pragma unroll
            for (int i = 0; i < 4; ++i) a[i] = As[k][ty * 4 + i];
            #pragma unroll
            for (int j = 0; j < 4; ++j) b[j] = Bs[k][tx * 4 + j];
            #pragma unroll
            for (int i = 0; i < 4; ++i)
                #pragma unroll
                for (int j = 0; j < 4; ++j)
                    acc[i][j] = fmaf(a[i], b[j], acc[i][j]);
        }
        __syncthreads();
    }

    #pragma unroll
    for (int i = 0; i < 4; ++i) {
        const int m = row0 + ty * 4 + i;
        const int n = col0 + tx * 4;
        float4 o;
        o.x = acc[i][0] + bias[n + 0];
        o.y = acc[i][1] + bias[n + 1];
        o.z = acc[i][2] + bias[n + 2];
        o.w = acc[i][3] + bias[n + 3];
        *(float4*)&C[(size_t)m * N + n] = o;
    }
}

// ---------------- loc + softmax (in place over OFF / ATT) ----------------
// grid = NROW blocks, 128 threads. thread tid -> h = tid/16, l = (tid/4)%4, p = tid%4.
__global__ __launch_bounds__(128) void loc_aw_kernel(
    float* __restrict__ off,            // [NROW,256] logits -> pixel coords (gx,gy)
    float* __restrict__ att,            // [NROW,128] logits -> softmaxed weights
    const float* __restrict__ refp)     // [NROW, LEVELS, 2]
{
    const int row = blockIdx.x;
    const int tid = threadIdx.x;        // == h*16 + l*4 + p
    const int l = (tid >> 2) & 3;

    // softmax over 16 (L*P) per head; each group of 16 lanes is one head
    float logit = att[(size_t)row * 128 + tid];
    float m = logit;
    #pragma unroll
    for (int d = 8; d >= 1; d >>= 1) m = fmaxf(m, __shfl_xor(m, d, 16));
    float e = __expf(logit - m);
    float s = e;
    #pragma unroll
    for (int d = 8; d >= 1; d >>= 1) s += __shfl_xor(s, d, 16);
    att[(size_t)row * 128 + tid] = e / s;

    // sampling location -> pixel coords (align_corners=False)
    const float ox = off[(size_t)row * 256 + tid * 2 + 0];
    const float oy = off[(size_t)row * 256 + tid * 2 + 1];
    const float rx = refp[(size_t)row * 8 + l * 2 + 0];
    const float ry = refp[(size_t)row * 8 + l * 2 + 1];
    const float Wl = (float)LVL_W[l];
    const float Hl = (float)LVL_H[l];
    const float lx = rx + ox / Wl;      // mimic reference op order
    const float ly = ry + oy / Hl;
    off[(size_t)row * 256 + tid * 2 + 0] = lx * Wl - 0.5f;
    off[(size_t)row * 256 + tid * 2 + 1] = ly * Hl - 0.5f;
}

// ---------------- bilinear sampling + weighted accumulation ----------------
// grid = NROW blocks, 256 threads. thread = (h = tid/32, c = tid%32).
// V layout: [b, pix, h, hd] (pix global over concatenated levels).
__global__ __launch_bounds__(256) void sample_kernel(
    const float* __restrict__ V,
    const float* __restrict__ LOC,      // [NROW,128,2] pixel coords
    const float* __restrict__ AW,       // [NROW,128]
    float* __restrict__ ACC)            // [NROW,256]  e = h*32 + c
{
    const int row = blockIdx.x;
    const int b   = row / LQ;
    const int tid = threadIdx.x;
    const int h   = tid >> 5;
    const int c   = tid & 31;

    const float* locr = LOC + (size_t)row * 256 + h * 32;   // 16 (gx,gy) pairs
    const float* awr  = AW  + (size_t)row * 128 + h * 16;
    const size_t vb   = (size_t)b * LQ * EMBED + h * HD + c;

    float acc = 0.f;
    #pragma unroll
    for (int l = 0; l < 4; ++l) {
        const int Wl = LVL_W[l], Hl = LVL_H[l], st = LVL_ST[l];
        #pragma unroll
        for (int p = 0; p < 4; ++p) {
            const int lp = l * 4 + p;
            const float gx = locr[lp * 2 + 0];
            const float gy = locr[lp * 2 + 1];
            const float w  = awr[lp];

            const float fx = floorf(gx), fy = floorf(gy);
            const float wx = gx - fx,    wy = gy - fy;
            const int x0 = (int)fx, y0 = (int)fy;
            const int x1 = x0 + 1,  y1 = y0 + 1;

            const float vx0 = (x0 >= 0 && x0 < Wl) ? 1.f : 0.f;
            const float vx1 = (x1 >= 0 && x1 < Wl) ? 1.f : 0.f;
            const float vy0 = (y0 >= 0 && y0 < Hl) ? 1.f : 0.f;
            const float vy1 = (y1 >= 0 && y1 < Hl) ? 1.f : 0.f;
            const int cx0 = min(max(x0, 0), Wl - 1);
            const int cx1 = min(max(x1, 0), Wl - 1);
            const int cy0 = min(max(y0, 0), Hl - 1);
            const int cy1 = min(max(y1, 0), Hl - 1);

            const float v00 = V[vb + (size_t)(st + cy0 * Wl + cx0) * EMBED];
            const float v01 = V[vb + (size_t)(st + cy0 * Wl + cx1) * EMBED];
            const float v10 = V[vb + (size_t)(st + cy1 * Wl + cx0) * EMBED];
            const float v11 = V[vb + (size_t)(st + cy1 * Wl + cx1) * EMBED];

            const float s =
                v00 * ((1.f - wx) * (1.f - wy) * vx0 * vy0) +
                v01 * ((wx) * (1.f - wy) * vx1 * vy0) +
                v10 * ((1.f - wx) * (wy) * vx0 * vy1) +
                v11 * ((wx) * (wy) * vx1 * vy1);
            acc = fmaf(w, s, acc);
        }
    }
    ACC[(size_t)row * 256 + tid] = acc;
}

// ---------------- launch ----------------
extern "C" void kernel_launch(void* const* d_in, const int* in_sizes, int n_in,
                              void* d_out, int out_size, void* d_ws, size_t ws_size,
                              hipStream_t stream) {
    const float* query  = (const float*)d_in[0];
    const float* refp   = (const float*)d_in[1];
    const float* value  = (const float*)d_in[2];
    // d_in[3] = value_spatial_shapes (static, hard-coded)
    const float* W_off  = (const float*)d_in[4];
    const float* b_off  = (const float*)d_in[5];
    const float* W_attn = (const float*)d_in[6];
    const float* b_attn = (const float*)d_in[7];
    const float* W_val  = (const float*)d_in[8];
    const float* b_val  = (const float*)d_in[9];
    const float* W_out  = (const float*)d_in[10];
    const float* b_out  = (const float*)d_in[11];
    float* out = (float*)d_out;

    float* ws  = (float*)d_ws;
    const size_t N_VE = (size_t)NROW * EMBED;    // 12,533,760
    float* V   = ws;                              // [NROW,256]
    float* OFF = V   + N_VE;                      // [NROW,256] -> becomes LOC
    float* ATT = OFF + N_VE;                      // [NROW,128] -> becomes AW
    float* ACC = ATT + (size_t)NROW * 128;        // [NROW,256]

    dim3 blk(256);
    dim3 g256(EMBED / BN, NROW / BM);   // N=256
    dim3 g128(128 / BN, NROW / BM);     // N=128

    // 1. V = value @ W_val + b_val
    gemm_bias<<<g256, blk, 0, stream>>>(value, W_val, b_val, V, NROW, EMBED, EMBED);
    // 2. offset / attention logits
    gemm_bias<<<g256, blk, 0, stream>>>(query, W_off, b_off, OFF, NROW, 256, EMBED);
    gemm_bias<<<g128, blk, 0, stream>>>(query, W_attn, b_attn, ATT, NROW, 128, EMBED);
    // 3. softmax + pixel coords (in place)
    loc_aw_kernel<<<NROW, 128, 0, stream>>>(OFF, ATT, refp);
    // 4. deformable sampling
    sample_kernel<<<NROW, 256, 0, stream>>>(V, OFF, ATT, ACC);
    // 5. out = ACC @ W_out + b_out
    gemm_bias<<<g256, blk, 0, stream>>>(ACC, W_out, b_out, out, NROW, EMBED, EMBED);
}

// Round 2
// 406.214 us; speedup vs baseline: 1.7321x; 1.7321x over previous
//
#include <hip/hip_runtime.h>
#include <hip/hip_bf16.h>

// ---------------- static problem constants ----------------
static constexpr int BS     = 4;
static constexpr int EMBED  = 256;
static constexpr int HEADS  = 8;
static constexpr int LEVELS = 4;
static constexpr int POINTS = 4;
static constexpr int HD     = 32;               // EMBED / HEADS
static constexpr int LQ     = 12240;            // sum of level areas
static constexpr int NROW   = BS * LQ;          // 48960 rows
static constexpr int LVL_W[4]  = {96, 48, 24, 12};
static constexpr int LVL_H[4]  = {96, 48, 24, 12};
static constexpr int LVL_ST[4] = {0, 9216, 11520, 12096};

typedef __attribute__((ext_vector_type(8))) short short8;  // bf16x8 MFMA frag
typedef __attribute__((ext_vector_type(4))) float f32x4;

__device__ __forceinline__ unsigned short f2bf(float f) {
    // round-to-nearest-even f32 -> bf16 (values are finite/normal here)
    unsigned int u = __float_as_uint(f);
    unsigned int r = (u + 0x7FFFu + ((u >> 16) & 1u)) >> 16;
    return (unsigned short)r;
}
__device__ __forceinline__ float bf2f(unsigned short b) {
    return __uint_as_float(((unsigned int)b) << 16);
}

// ---------------- weight prep: transpose + f32->bf16 ----------------
// WT_oa [384][256] = concat(W_off^T, W_attn^T); WT_val/WT_out [256][256].
__global__ __launch_bounds__(256) void prep_weights(
    const float* __restrict__ W_off, const float* __restrict__ W_attn,
    const float* __restrict__ W_val, const float* __restrict__ W_out,
    unsigned short* __restrict__ WT_oa, unsigned short* __restrict__ WT_val,
    unsigned short* __restrict__ WT_out)
{
    const int gid = blockIdx.x * 256 + threadIdx.x;   // 896*256 total
    const int k = gid & 255;
    const int n = gid >> 8;
    if (n < 384) {
        const float v = (n < 256) ? W_off[k * 256 + n] : W_attn[k * 128 + (n - 256)];
        WT_oa[n * 256 + k] = f2bf(v);
    } else if (n < 640) {
        const int nn = n - 384;
        WT_val[nn * 256 + k] = f2bf(W_val[k * 256 + nn]);
    } else {
        const int nn = n - 640;
        WT_out[nn * 256 + k] = f2bf(W_out[k * 256 + nn]);
    }
}

// ---------------- bf16 MFMA GEMM: C[M,N] = A[M,256] @ Wt^T + bias ----------------
// Wt is [N][K=256] bf16 (pre-transposed). BM=BN=64, BK=32, 256 threads = 4 waves,
// wave w computes rows [w*16, w*16+16) x 64 cols via 4 accumulators.
// A-frag layout: A[m=lane&15][k=(lane>>4)*8+j]; B-frag: B[k=(lane>>4)*8+j][n=lane&15];
// D: col=lane&15, row=(lane>>4)*4+reg (HW-verified mappings).
template <bool A_BF16, bool OUT_BF16>
__global__ __launch_bounds__(256) void gemm_mfma(
    const void* __restrict__ Av, const unsigned short* __restrict__ Wt,
    const float* __restrict__ bias0, const float* __restrict__ bias1, int nsplit,
    void* __restrict__ Cv, int N)
{
    constexpr int K = 256;
    __shared__ __align__(16) unsigned short As[64][40];  // [m][k], stride 40 keeps 16B align
    __shared__ __align__(16) unsigned short Bs[64][40];  // [n][k]

    const int tid = threadIdx.x;
    const int m0 = blockIdx.y * 64;
    const int n0 = blockIdx.x * 64;
    const int w  = tid >> 6;
    const int l  = tid & 63;
    const int lm = l & 15;
    const int lq = l >> 4;

    const int sm = tid >> 2;          // staging row 0..63
    const int kg = (tid & 3) * 8;     // staging k offset 0,8,16,24

    f32x4 acc[4] = {{0.f,0.f,0.f,0.f},{0.f,0.f,0.f,0.f},{0.f,0.f,0.f,0.f},{0.f,0.f,0.f,0.f}};

    for (int k0 = 0; k0 < K; k0 += 32) {
        // ---- stage A tile (64 x 32) ----
        if (A_BF16) {
            const unsigned short* A = (const unsigned short*)Av;
            *(short8*)&As[sm][kg] = *(const short8*)&A[(size_t)(m0 + sm) * K + k0 + kg];
        } else {
            const float* A = (const float*)Av;
            const float* ap = &A[(size_t)(m0 + sm) * K + k0 + kg];
            const float4 x = *(const float4*)ap;
            const float4 y = *(const float4*)(ap + 4);
            uint4 pk;
            pk.x = (unsigned int)f2bf(x.x) | ((unsigned int)f2bf(x.y) << 16);
            pk.y = (unsigned int)f2bf(x.z) | ((unsigned int)f2bf(x.w) << 16);
            pk.z = (unsigned int)f2bf(y.x) | ((unsigned int)f2bf(y.y) << 16);
            pk.w = (unsigned int)f2bf(y.z) | ((unsigned int)f2bf(y.w) << 16);
            *(uint4*)&As[sm][kg] = pk;
        }
        // ---- stage B tile (64 x 32) from Wt[N][K] ----
        *(short8*)&Bs[sm][kg] = *(const short8*)&Wt[(size_t)(n0 + sm) * K + k0 + kg];
        __syncthreads();

        const short8 af = *(const short8*)&As[w * 16 + lm][lq * 8];
        #pragma unroll
        for (int nt = 0; nt < 4; ++nt) {
            const short8 bf = *(const short8*)&Bs[nt * 16 + lm][lq * 8];
            acc[nt] = __builtin_amdgcn_mfma_f32_16x16x32_bf16(af, bf, acc[nt], 0, 0, 0);
        }
        __syncthreads();
    }

    // ---- epilogue ----
    #pragma unroll
    for (int nt = 0; nt < 4; ++nt) {
        const int col = n0 + nt * 16 + lm;
        const float b = (col < nsplit) ? bias0[col] : bias1[col - nsplit];
        #pragma unroll
        for (int r = 0; r < 4; ++r) {
            const int row = m0 + w * 16 + lq * 4 + r;
            const float v = acc[nt][r] + b;
            if (OUT_BF16) ((unsigned short*)Cv)[(size_t)row * N + col] = f2bf(v);
            else          ((float*)Cv)[(size_t)row * N + col] = v;
        }
    }
}

// ---------------- loc + softmax (in place over OA [row][384]) ----------------
// cols 0..255: offset logits -> pixel coords; cols 256..383: attn logits -> weights.
__global__ __launch_bounds__(128) void loc_aw_kernel(
    float* __restrict__ OA, const float* __restrict__ refp)
{
    const int row = blockIdx.x;
    const int tid = threadIdx.x;        // == h*16 + l*4 + p
    const int l = (tid >> 2) & 3;
    float* rowp = OA + (size_t)row * 384;

    // softmax over 16 (L*P) per head; each group of 16 lanes is one head
    float logit = rowp[256 + tid];
    float m = logit;
    #pragma unroll
    for (int d = 8; d >= 1; d >>= 1) m = fmaxf(m, __shfl_xor(m, d, 16));
    float e = __expf(logit - m);
    float s = e;
    #pragma unroll
    for (int d = 8; d >= 1; d >>= 1) s += __shfl_xor(s, d, 16);
    rowp[256 + tid] = e / s;

    // sampling location -> pixel coords (align_corners=False)
    const float ox = rowp[tid * 2 + 0];
    const float oy = rowp[tid * 2 + 1];
    const float rx = refp[(size_t)row * 8 + l * 2 + 0];
    const float ry = refp[(size_t)row * 8 + l * 2 + 1];
    const float Wl = (float)LVL_W[l];
    const float Hl = (float)LVL_H[l];
    const float lx = rx + ox / Wl;      // mimic reference op order
    const float ly = ry + oy / Hl;
    rowp[tid * 2 + 0] = lx * Wl - 0.5f;
    rowp[tid * 2 + 1] = ly * Hl - 0.5f;
}

// ---------------- bilinear sampling + weighted accumulation (bf16 V) ----------------
// 64 threads per row: t -> h = t/8, c4 = t%8 (4 channels each, ushort4 loads).
// Block = 256 threads = 4 rows; wave = one full row.
__global__ __launch_bounds__(256) void sample_kernel(
    const unsigned short* __restrict__ V,   // bf16 [b, pix, 256]
    const float* __restrict__ OA,           // [row][384]: coords then weights
    unsigned short* __restrict__ ACC)       // bf16 [row][256]
{
    const int tid = threadIdx.x;
    const int row = blockIdx.x * 4 + (tid >> 6);
    const int t  = tid & 63;
    const int h  = t >> 3;
    const int c4 = t & 7;
    const int b  = blockIdx.x / 3060;       // 3060 blocks per batch (12240/4)

    const float* locr = OA + (size_t)row * 384 + h * 32;        // 16 (gx,gy)
    const float* awr  = OA + (size_t)row * 384 + 256 + h * 16;  // 16 weights
    const unsigned short* vb = V + ((size_t)b * LQ * EMBED + h * HD + c4 * 4);

    float ax = 0.f, ay = 0.f, az = 0.f, aw4 = 0.f;
    #pragma unroll
    for (int l = 0; l < 4; ++l) {
        const int Wl = LVL_W[l], Hl = LVL_H[l], st = LVL_ST[l];
        #pragma unroll
        for (int p = 0; p < 4; ++p) {
            const int lp = l * 4 + p;
            const float gx = locr[lp * 2 + 0];
            const float gy = locr[lp * 2 + 1];
            const float wgt = awr[lp];

            const float fx = floorf(gx), fy = floorf(gy);
            const float wx = gx - fx,    wy = gy - fy;
            const int x0 = (int)fx, y0 = (int)fy;
            const int x1 = x0 + 1,  y1 = y0 + 1;

            const bool bx0 = ((unsigned)x0 < (unsigned)Wl);
            const bool bx1 = ((unsigned)x1 < (unsigned)Wl);
            const bool by0 = ((unsigned)y0 < (unsigned)Hl);
            const bool by1 = ((unsigned)y1 < (unsigned)Hl);
            const float w00 = (bx0 && by0) ? (1.f - wx) * (1.f - wy) * wgt : 0.f;
            const float w01 = (bx1 && by0) ? wx * (1.f - wy) * wgt : 0.f;
            const float w10 = (bx0 && by1) ? (1.f - wx) * wy * wgt : 0.f;
            const float w11 = (bx1 && by1) ? wx * wy * wgt : 0.f;

            const int cx0 = min(max(x0, 0), Wl - 1);
            const int cx1 = min(max(x1, 0), Wl - 1);
            const int cy0 = min(max(y0, 0), Hl - 1);
            const int cy1 = min(max(y1, 0), Hl - 1);
            const int i00 = (st + cy0 * Wl + cx0) * EMBED;
            const int i01 = (st + cy0 * Wl + cx1) * EMBED;
            const int i10 = (st + cy1 * Wl + cx0) * EMBED;
            const int i11 = (st + cy1 * Wl + cx1) * EMBED;

            const ushort4 u00 = *(const ushort4*)(vb + i00);
            const ushort4 u01 = *(const ushort4*)(vb + i01);
            const ushort4 u10 = *(const ushort4*)(vb + i10);
            const ushort4 u11 = *(const ushort4*)(vb + i11);

            ax = fmaf(w00, bf2f(u00.x), ax); ay = fmaf(w00, bf2f(u00.y), ay);
            az = fmaf(w00, bf2f(u00.z), az); aw4 = fmaf(w00, bf2f(u00.w), aw4);
            ax = fmaf(w01, bf2f(u01.x), ax); ay = fmaf(w01, bf2f(u01.y), ay);
            az = fmaf(w01, bf2f(u01.z), az); aw4 = fmaf(w01, bf2f(u01.w), aw4);
            ax = fmaf(w10, bf2f(u10.x), ax); ay = fmaf(w10, bf2f(u10.y), ay);
            az = fmaf(w10, bf2f(u10.z), az); aw4 = fmaf(w10, bf2f(u10.w), aw4);
            ax = fmaf(w11, bf2f(u11.x), ax); ay = fmaf(w11, bf2f(u11.y), ay);
            az = fmaf(w11, bf2f(u11.z), az); aw4 = fmaf(w11, bf2f(u11.w), aw4);
        }
    }
    ushort4 o;
    o.x = f2bf(ax); o.y = f2bf(ay); o.z = f2bf(az); o.w = f2bf(aw4);
    *(ushort4*)(ACC + (size_t)row * EMBED + h * HD + c4 * 4) = o;
}

// ---------------- launch ----------------
extern "C" void kernel_launch(void* const* d_in, const int* in_sizes, int n_in,
                              void* d_out, int out_size, void* d_ws, size_t ws_size,
                              hipStream_t stream) {
    const float* query  = (const float*)d_in[0];
    const float* refp   = (const float*)d_in[1];
    const float* value  = (const float*)d_in[2];
    // d_in[3] = value_spatial_shapes (static, hard-coded)
    const float* W_off  = (const float*)d_in[4];
    const float* b_off  = (const float*)d_in[5];
    const float* W_attn = (const float*)d_in[6];
    const float* b_attn = (const float*)d_in[7];
    const float* W_val  = (const float*)d_in[8];
    const float* b_val  = (const float*)d_in[9];
    const float* W_out  = (const float*)d_in[10];
    const float* b_out  = (const float*)d_in[11];
    float* out = (float*)d_out;

    // ---- workspace layout ----
    unsigned short* WT_oa  = (unsigned short*)d_ws;          // [384][256] bf16
    unsigned short* WT_val = WT_oa  + 384 * 256;             // [256][256] bf16
    unsigned short* WT_out = WT_val + 256 * 256;             // [256][256] bf16
    unsigned short* V      = WT_out + 256 * 256;             // [NROW][256] bf16
    float*          OA     = (float*)(V + (size_t)NROW * EMBED);   // [NROW][384] f32
    unsigned short* ACCb   = (unsigned short*)(OA + (size_t)NROW * 384); // [NROW][256] bf16

    dim3 blk(256);

    // 0. weight transpose + convert (896 blocks)
    prep_weights<<<896, blk, 0, stream>>>(W_off, W_attn, W_val, W_out,
                                          WT_oa, WT_val, WT_out);
    // 1. V = bf16(value @ W_val + b_val)
    gemm_mfma<false, true><<<dim3(4, NROW / 64), blk, 0, stream>>>(
        value, WT_val, b_val, b_val, 256, V, EMBED);
    // 2. OA = query @ [W_off | W_attn] + [b_off | b_attn]   (N = 384)
    gemm_mfma<false, false><<<dim3(6, NROW / 64), blk, 0, stream>>>(
        query, WT_oa, b_off, b_attn, 256, OA, 384);
    // 3. softmax + pixel coords (in place over OA)
    loc_aw_kernel<<<NROW, 128, 0, stream>>>(OA, refp);
    // 4. deformable sampling -> bf16 ACC
    sample_kernel<<<NROW / 4, blk, 0, stream>>>(V, OA, ACCb);
    // 5. out = ACC @ W_out + b_out
    gemm_mfma<true, false><<<dim3(4, NROW / 64), blk, 0, stream>>>(
        ACCb, WT_out, b_out, b_out, 256, out, EMBED);
}

// Round 3
// 403.033 us; speedup vs baseline: 1.7458x; 1.0079x over previous
//
#include <hip/hip_runtime.h>
#include <hip/hip_bf16.h>

// ---------------- static problem constants ----------------
static constexpr int BS     = 4;
static constexpr int EMBED  = 256;
static constexpr int HEADS  = 8;
static constexpr int LEVELS = 4;
static constexpr int POINTS = 4;
static constexpr int HD     = 32;               // EMBED / HEADS
static constexpr int LQ     = 12240;            // sum of level areas
static constexpr int NROW   = BS * LQ;          // 48960 rows
static constexpr int LVL_W[4]  = {96, 48, 24, 12};
static constexpr int LVL_H[4]  = {96, 48, 24, 12};
static constexpr int LVL_ST[4] = {0, 9216, 11520, 12096};

typedef __attribute__((ext_vector_type(8))) short short8;            // bf16x8 MFMA frag
typedef __attribute__((ext_vector_type(4))) float f32x4;
typedef __attribute__((ext_vector_type(8))) unsigned short ushort8v;

__device__ __forceinline__ unsigned short f2bf(float f) {
    unsigned int u = __float_as_uint(f);
    unsigned int r = (u + 0x7FFFu + ((u >> 16) & 1u)) >> 16;   // RNE
    return (unsigned short)r;
}
__device__ __forceinline__ float bf2f(unsigned short b) {
    return __uint_as_float(((unsigned int)b) << 16);
}

// ---------------- weight prep: transpose + f32->bf16 ----------------
__global__ __launch_bounds__(256) void prep_weights(
    const float* __restrict__ W_off, const float* __restrict__ W_attn,
    const float* __restrict__ W_val, const float* __restrict__ W_out,
    unsigned short* __restrict__ WT_oa, unsigned short* __restrict__ WT_val,
    unsigned short* __restrict__ WT_out)
{
    const int gid = blockIdx.x * 256 + threadIdx.x;   // 896*256 total
    const int k = gid & 255;
    const int n = gid >> 8;
    if (n < 384) {
        const float v = (n < 256) ? W_off[k * 256 + n] : W_attn[k * 128 + (n - 256)];
        WT_oa[n * 256 + k] = f2bf(v);
    } else if (n < 640) {
        const int nn = n - 384;
        WT_val[nn * 256 + k] = f2bf(W_val[k * 256 + nn]);
    } else {
        const int nn = n - 640;
        WT_out[nn * 256 + k] = f2bf(W_out[k * 256 + nn]);
    }
}

// ---------------- bf16 MFMA GEMM: C[M,N] = A[M,256] @ Wt^T + bias ----------------
// Block = 64 rows x NB=NTW*64 cols, 256 threads = 4 waves. Waves split by COLUMN:
// wave w owns col-frags [w*NTW, (w+1)*NTW), each frag 16 cols, across all 64 rows
// (4 row-groups of 16). Per K-step (BK=32) a wave does 4*NTW MFMAs / (4+NTW) ds_reads.
// A-frag: A[m=lane&15][k=(lane>>4)*8+j]; B-frag: B[k][n=lane&15]; D: col=lane&15,
// row=(lane>>4)*4+reg (HW-verified mappings).
template <int NTW, bool A_BF16, bool OUT_BF16>
__global__ __launch_bounds__(256) void gemm_mfma(
    const void* __restrict__ Av, const unsigned short* __restrict__ Wt,
    const float* __restrict__ bias0, const float* __restrict__ bias1, int nsplit,
    void* __restrict__ Cv, int N)
{
    constexpr int NB = NTW * 64;
    constexpr int K  = 256;
    __shared__ __align__(16) unsigned short As[64][40];   // [m][k], stride 40: 16B-aligned, 2-way max
    __shared__ __align__(16) unsigned short Bs[NB][40];   // [n][k]

    const int tid = threadIdx.x;
    const int m0 = blockIdx.y * 64;
    const int n0 = blockIdx.x * NB;
    const int w  = tid >> 6;
    const int l  = tid & 63;
    const int lm = l & 15;
    const int lq = l >> 4;

    const int sr = tid >> 2;          // staging row 0..63
    const int kg = (tid & 3) * 8;     // staging k offset 0,8,16,24

    f32x4 acc[4][NTW];
    #pragma unroll
    for (int rg = 0; rg < 4; ++rg)
        #pragma unroll
        for (int nt = 0; nt < NTW; ++nt)
            acc[rg][nt] = (f32x4){0.f, 0.f, 0.f, 0.f};

    for (int k0 = 0; k0 < K; k0 += 32) {
        // ---- stage A tile (64 x 32) ----
        if (A_BF16) {
            const unsigned short* A = (const unsigned short*)Av;
            *(short8*)&As[sr][kg] = *(const short8*)&A[(size_t)(m0 + sr) * K + k0 + kg];
        } else {
            const float* A = (const float*)Av;
            const float* ap = &A[(size_t)(m0 + sr) * K + k0 + kg];
            const float4 x = *(const float4*)ap;
            const float4 y = *(const float4*)(ap + 4);
            uint4 pk;
            pk.x = (unsigned int)f2bf(x.x) | ((unsigned int)f2bf(x.y) << 16);
            pk.y = (unsigned int)f2bf(x.z) | ((unsigned int)f2bf(x.w) << 16);
            pk.z = (unsigned int)f2bf(y.x) | ((unsigned int)f2bf(y.y) << 16);
            pk.w = (unsigned int)f2bf(y.z) | ((unsigned int)f2bf(y.w) << 16);
            *(uint4*)&As[sr][kg] = pk;
        }
        // ---- stage B tile (NB x 32) from Wt[N][K] ----
        #pragma unroll
        for (int i = 0; i < NTW; ++i) {
            const int slot = tid + i * 256;
            const int n  = slot >> 2;
            const int kk = (slot & 3) * 8;
            *(short8*)&Bs[n][kk] = *(const short8*)&Wt[(size_t)(n0 + n) * K + k0 + kk];
        }
        __syncthreads();

        short8 af[4];
        #pragma unroll
        for (int rg = 0; rg < 4; ++rg)
            af[rg] = *(const short8*)&As[rg * 16 + lm][lq * 8];
        #pragma unroll
        for (int nt = 0; nt < NTW; ++nt) {
            const short8 bf = *(const short8*)&Bs[(w * NTW + nt) * 16 + lm][lq * 8];
            #pragma unroll
            for (int rg = 0; rg < 4; ++rg)
                acc[rg][nt] = __builtin_amdgcn_mfma_f32_16x16x32_bf16(af[rg], bf, acc[rg][nt], 0, 0, 0);
        }
        __syncthreads();
    }

    // ---- epilogue ----
    #pragma unroll
    for (int nt = 0; nt < NTW; ++nt) {
        const int col = n0 + (w * NTW + nt) * 16 + lm;
        const float b = (col < nsplit) ? bias0[col] : bias1[col - nsplit];
        #pragma unroll
        for (int rg = 0; rg < 4; ++rg) {
            #pragma unroll
            for (int r = 0; r < 4; ++r) {
                const int row = m0 + rg * 16 + lq * 4 + r;
                const float v = acc[rg][nt][r] + b;
                if (OUT_BF16) ((unsigned short*)Cv)[(size_t)row * N + col] = f2bf(v);
                else          ((float*)Cv)[(size_t)row * N + col] = v;
            }
        }
    }
}

// ---------------- loc + softmax (in place over OA [row][384]) ----------------
__global__ __launch_bounds__(128) void loc_aw_kernel(
    float* __restrict__ OA, const float* __restrict__ refp)
{
    const int row = blockIdx.x;
    const int tid = threadIdx.x;        // == h*16 + l*4 + p
    const int l = (tid >> 2) & 3;
    float* rowp = OA + (size_t)row * 384;

    float logit = rowp[256 + tid];
    float m = logit;
    #pragma unroll
    for (int d = 8; d >= 1; d >>= 1) m = fmaxf(m, __shfl_xor(m, d, 16));
    float e = __expf(logit - m);
    float s = e;
    #pragma unroll
    for (int d = 8; d >= 1; d >>= 1) s += __shfl_xor(s, d, 16);
    rowp[256 + tid] = e / s;

    const float ox = rowp[tid * 2 + 0];
    const float oy = rowp[tid * 2 + 1];
    const float rx = refp[(size_t)row * 8 + l * 2 + 0];
    const float ry = refp[(size_t)row * 8 + l * 2 + 1];
    const float Wl = (float)LVL_W[l];
    const float Hl = (float)LVL_H[l];
    const float lx = rx + ox / Wl;      // mimic reference op order
    const float ly = ry + oy / Hl;
    rowp[tid * 2 + 0] = lx * Wl - 0.5f;
    rowp[tid * 2 + 1] = ly * Hl - 0.5f;
}

// ---------------- bilinear sampling + weighted accumulation (bf16 V) ----------------
// 32 threads per row: t -> h = t/4, c8 = (t%4)*8 (8 channels each, ushort8 = 16B loads).
// Block = 256 threads = 8 rows. XCD swizzle: bid%8 = XCD; 2 XCDs per batch so each
// XCD's gather working set is one batch's V (~6.3 MB).
__global__ __launch_bounds__(256) void sample_kernel(
    const unsigned short* __restrict__ V,   // bf16 [b, pix, 256]
    const float* __restrict__ OA,           // [row][384]: coords then weights
    unsigned short* __restrict__ ACC)       // bf16 [row][256]
{
    const int tid  = threadIdx.x;
    const int bid  = blockIdx.x;            // NROW/8 = 6120 = 8*765
    const int xcd  = bid & 7;
    const int slot = bid >> 3;              // 0..764
    const int batch = xcd >> 1;             // 2 XCDs per batch
    const int group = slot * 2 + (xcd & 1); // 0..1529
    const int row  = batch * LQ + group * 8 + (tid >> 5);
    const int t  = tid & 31;
    const int h  = t >> 2;
    const int c8 = (t & 3) * 8;

    const float* locr = OA + (size_t)row * 384 + h * 32;        // 16 (gx,gy)
    const float* awr  = OA + (size_t)row * 384 + 256 + h * 16;  // 16 weights
    const unsigned short* vb = V + ((size_t)batch * LQ * EMBED + h * HD + c8);

    float a[8];
    #pragma unroll
    for (int j = 0; j < 8; ++j) a[j] = 0.f;

    #pragma unroll
    for (int l = 0; l < 4; ++l) {
        const int Wl = LVL_W[l], Hl = LVL_H[l], st = LVL_ST[l];
        #pragma unroll
        for (int p = 0; p < 4; ++p) {
            const int lp = l * 4 + p;
            const float gx = locr[lp * 2 + 0];
            const float gy = locr[lp * 2 + 1];
            const float wgt = awr[lp];

            const float fx = floorf(gx), fy = floorf(gy);
            const float wx = gx - fx,    wy = gy - fy;
            const int x0 = (int)fx, y0 = (int)fy;
            const int x1 = x0 + 1,  y1 = y0 + 1;

            const bool bx0 = ((unsigned)x0 < (unsigned)Wl);
            const bool bx1 = ((unsigned)x1 < (unsigned)Wl);
            const bool by0 = ((unsigned)y0 < (unsigned)Hl);
            const bool by1 = ((unsigned)y1 < (unsigned)Hl);
            const float w00 = (bx0 && by0) ? (1.f - wx) * (1.f - wy) * wgt : 0.f;
            const float w01 = (bx1 && by0) ? wx * (1.f - wy) * wgt : 0.f;
            const float w10 = (bx0 && by1) ? (1.f - wx) * wy * wgt : 0.f;
            const float w11 = (bx1 && by1) ? wx * wy * wgt : 0.f;

            const int cx0 = min(max(x0, 0), Wl - 1);
            const int cx1 = min(max(x1, 0), Wl - 1);
            const int cy0 = min(max(y0, 0), Hl - 1);
            const int cy1 = min(max(y1, 0), Hl - 1);
            const int i00 = (st + cy0 * Wl + cx0) * EMBED;
            const int i01 = (st + cy0 * Wl + cx1) * EMBED;
            const int i10 = (st + cy1 * Wl + cx0) * EMBED;
            const int i11 = (st + cy1 * Wl + cx1) * EMBED;

            const ushort8v u00 = *(const ushort8v*)(vb + i00);
            const ushort8v u01 = *(const ushort8v*)(vb + i01);
            const ushort8v u10 = *(const ushort8v*)(vb + i10);
            const ushort8v u11 = *(const ushort8v*)(vb + i11);

            #pragma unroll
            for (int j = 0; j < 8; ++j) {
                float aj = a[j];
                aj = fmaf(w00, bf2f(u00[j]), aj);
                aj = fmaf(w01, bf2f(u01[j]), aj);
                aj = fmaf(w10, bf2f(u10[j]), aj);
                aj = fmaf(w11, bf2f(u11[j]), aj);
                a[j] = aj;
            }
        }
    }
    ushort8v o;
    #pragma unroll
    for (int j = 0; j < 8; ++j) o[j] = f2bf(a[j]);
    *(ushort8v*)(ACC + (size_t)row * EMBED + h * HD + c8) = o;
}

// ---------------- launch ----------------
extern "C" void kernel_launch(void* const* d_in, const int* in_sizes, int n_in,
                              void* d_out, int out_size, void* d_ws, size_t ws_size,
                              hipStream_t stream) {
    const float* query  = (const float*)d_in[0];
    const float* refp   = (const float*)d_in[1];
    const float* value  = (const float*)d_in[2];
    // d_in[3] = value_spatial_shapes (static, hard-coded)
    const float* W_off  = (const float*)d_in[4];
    const float* b_off  = (const float*)d_in[5];
    const float* W_attn = (const float*)d_in[6];
    const float* b_attn = (const float*)d_in[7];
    const float* W_val  = (const float*)d_in[8];
    const float* b_val  = (const float*)d_in[9];
    const float* W_out  = (const float*)d_in[10];
    const float* b_out  = (const float*)d_in[11];
    float* out = (float*)d_out;

    // ---- workspace layout ----
    unsigned short* WT_oa  = (unsigned short*)d_ws;          // [384][256] bf16
    unsigned short* WT_val = WT_oa  + 384 * 256;             // [256][256] bf16
    unsigned short* WT_out = WT_val + 256 * 256;             // [256][256] bf16
    unsigned short* V      = WT_out + 256 * 256;             // [NROW][256] bf16
    float*          OA     = (float*)(V + (size_t)NROW * EMBED);        // [NROW][384] f32
    unsigned short* ACCb   = (unsigned short*)(OA + (size_t)NROW * 384); // [NROW][256] bf16

    dim3 blk(256);

    // 0. weight transpose + convert
    prep_weights<<<896, blk, 0, stream>>>(W_off, W_attn, W_val, W_out,
                                          WT_oa, WT_val, WT_out);
    // 1. V = bf16(value @ W_val + b_val)      (64 x 256 blocks)
    gemm_mfma<4, false, true><<<dim3(1, NROW / 64), blk, 0, stream>>>(
        value, WT_val, b_val, b_val, 256, V, 256);
    // 2. OA = query @ [W_off | W_attn] + bias (64 x 192 blocks, N=384)
    gemm_mfma<3, false, false><<<dim3(2, NROW / 64), blk, 0, stream>>>(
        query, WT_oa, b_off, b_attn, 256, OA, 384);
    // 3. softmax + pixel coords (in place over OA)
    loc_aw_kernel<<<NROW, 128, 0, stream>>>(OA, refp);
    // 4. deformable sampling -> bf16 ACC
    sample_kernel<<<NROW / 8, blk, 0, stream>>>(V, OA, ACCb);
    // 5. out = ACC @ W_out + b_out
    gemm_mfma<4, true, false><<<dim3(1, NROW / 64), blk, 0, stream>>>(
        ACCb, WT_out, b_out, b_out, 256, out, 256);
}